// Round 1
// baseline (861.330 us; speedup 1.0000x reference)
//
#include <hip/hip_runtime.h>
#include <cmath>

#define NPTS 131072
#define MS   65536
#define NNB  32
#define KKP  15
#define INF  64
#define OUTF 128
#define KCDIM (KKP*OUTF)   // 1920

typedef __attribute__((ext_vector_type(8))) __bf16 bf16x8;
typedef __attribute__((ext_vector_type(4))) float f32x4;

__device__ __forceinline__ float bf2f(unsigned int u16v){
  unsigned int x = u16v << 16;
  return __builtin_bit_cast(float, x);
}
__device__ __forceinline__ unsigned int f2bf(float f){
  unsigned int u = __builtin_bit_cast(unsigned int, f);
  unsigned int r = u + 0x7fffu + ((u >> 16) & 1u);
  return r >> 16;
}
__device__ __forceinline__ float leaky(float v){ return v >= 0.f ? v : 0.01f * v; }

// ---------------- K0: weight transpose + bf16 convert ----------------
__global__ __launch_bounds__(256) void k_cvt_67723(
    const float* __restrict__ kpw, const float* __restrict__ wpost,
    const float* __restrict__ wsc,
    unsigned short* __restrict__ kpwT, unsigned short* __restrict__ wpostT,
    unsigned short* __restrict__ wscT)
{
  int tid = blockIdx.x * 256 + threadIdx.x;
  if (tid < OUTF * KCDIM) {                       // kpwT[o][kc] = kpw[kc*128+o]
    int o = tid / KCDIM, kc = tid % KCDIM;
    kpwT[tid] = (unsigned short)f2bf(kpw[(size_t)kc * OUTF + o]);
    return;
  }
  int t2 = tid - OUTF * KCDIM;
  if (t2 < OUTF * OUTF) {                         // wpostT[out][in]
    int o = t2 / OUTF, i = t2 % OUTF;
    wpostT[t2] = (unsigned short)f2bf(wpost[i * OUTF + o]);
    return;
  }
  int t3 = t2 - OUTF * OUTF;
  if (t3 < OUTF * INF) {                          // wscT[out][in]
    int o = t3 / INF, c = t3 % INF;
    wscT[t3] = (unsigned short)f2bf(wsc[c * OUTF + o]);
  }
}

// ---------------- K1: pre layer: feats = leaky(features @ W_pre + b_pre), bf16 ----
__global__ __launch_bounds__(256) void k_pre_67723(
    const float* __restrict__ feat, const float* __restrict__ Wp,
    const float* __restrict__ bp, unsigned short* __restrict__ outbf)
{
  int gid = blockIdx.x * 256 + threadIdx.x;
  int row = gid >> 3;
  int oc0 = (gid & 7) << 4;
  float acc[16];
#pragma unroll
  for (int j = 0; j < 16; j++) acc[j] = bp[oc0 + j];
  const float* frow = feat + (size_t)row * INF;
#pragma unroll
  for (int k = 0; k < INF; k += 4) {
    float4 f = *(const float4*)(frow + k);
    float fa[4] = {f.x, f.y, f.z, f.w};
#pragma unroll
    for (int i = 0; i < 4; i++) {
      const float4* wr = (const float4*)(Wp + (size_t)(k + i) * OUTF + oc0);
#pragma unroll
      for (int j4 = 0; j4 < 4; j4++) {
        float4 wv = wr[j4];
        acc[j4*4+0] += fa[i]*wv.x; acc[j4*4+1] += fa[i]*wv.y;
        acc[j4*4+2] += fa[i]*wv.z; acc[j4*4+3] += fa[i]*wv.w;
      }
    }
  }
  unsigned int pk[8];
#pragma unroll
  for (int j = 0; j < 8; j++) {
    float a = leaky(acc[2*j]), b = leaky(acc[2*j+1]);
    pk[j] = f2bf(a) | (f2bf(b) << 16);
  }
  uint4* dst = (uint4*)(outbf + (size_t)row * OUTF + oc0);
  dst[0] = make_uint4(pk[0], pk[1], pk[2], pk[3]);
  dst[1] = make_uint4(pk[4], pk[5], pk[6], pk[7]);
}

// ---------------- K2: fused KPConv + post + shortcut ----------------
// Block = 32 samples, 256 threads (4 waves). LDS: wfeat(swizzled bf16) + a2 + a3 + w + nbr
__global__ __launch_bounds__(256) void k_fused_67723(
    const float* __restrict__ points, const float* __restrict__ features,
    const float* __restrict__ kp, const float* __restrict__ bpost,
    const float* __restrict__ bsc, const int* __restrict__ sample_idx,
    const int* __restrict__ nbr, const unsigned short* __restrict__ featbf,
    const unsigned short* __restrict__ kpwT, const unsigned short* __restrict__ wpostT,
    const unsigned short* __restrict__ wscT, float* __restrict__ out,
    float inv_ext)
{
  extern __shared__ char smem[];
  unsigned short* wf = (unsigned short*)smem;          // 32 x 1920 bf16, row stride 3840 B (swz)
  char* a2 = smem + 122880;                            // 32 x 128 bf16 (swz)     8192 B
  char* a3 = smem + 131072;                            // 32 x 64 bf16 (swz)      4096 B
  float* wl = (float*)(smem + 135168);                 // [4][32][16] f32         8192 B
  unsigned int* nb = (unsigned int*)(smem + 143360);   // [4][32] byte offsets     512 B

  const int t = threadIdx.x;
  const int l = t & 63;
  const int w = t >> 6;
  const int m0 = blockIdx.x * 32;

  // stage a3: gathered raw features rows -> bf16 (for shortcut GEMM)
  {
    int s = t >> 3, seg = t & 7;
    int sidx = sample_idx[m0 + s];
    const float* src = features + (size_t)sidx * INF + seg * 8;
    float4 f0 = *(const float4*)src;
    float4 f1 = *(const float4*)(src + 4);
    uint4 p;
    p.x = f2bf(f0.x) | (f2bf(f0.y) << 16);
    p.y = f2bf(f0.z) | (f2bf(f0.w) << 16);
    p.z = f2bf(f1.x) | (f2bf(f1.y) << 16);
    p.w = f2bf(f1.z) | (f2bf(f1.w) << 16);
    *(uint4*)(a3 + s * 128 + ((seg * 16) ^ ((s & 7) << 4))) = p;
  }

  float kpx[KKP], kpy[KKP], kpz[KKP];
#pragma unroll
  for (int k = 0; k < KKP; k++) { kpx[k] = kp[k*3]; kpy[k] = kp[k*3+1]; kpz[k] = kp[k*3+2]; }

  // ---- phase A: per-wave, 8 samples each: influence weights + gather-accumulate wfeat ----
  for (int si = 0; si < 8; si++) {
    int s = w * 8 + si;
    int gm = m0 + s;
    if (l < 32) {
      int sidx = sample_idx[gm];
      float qx = points[sidx*3+0], qy = points[sidx*3+1], qz = points[sidx*3+2];
      int ni = nbr[gm * NNB + l];
      bool valid = ni < NPTS;                 // ni == NPTS is shadow (w=0, feat=0)
      int nic = valid ? ni : 0;               // clamp; weight forced to 0
      nb[w*32 + l] = (unsigned int)nic * (OUTF * 2);
      float px = points[nic*3+0], py = points[nic*3+1], pz = points[nic*3+2];
      float dx = px - qx, dy = py - qy, dz = pz - qz;
      float* wrow = wl + (w*32 + l) * 16;
#pragma unroll
      for (int k = 0; k < KKP; k++) {
        float ex = dx - kpx[k], ey = dy - kpy[k], ez = dz - kpz[k];
        float d = sqrtf(ex*ex + ey*ey + ez*ez);
        float wv = fmaxf(1.f - d * inv_ext, 0.f);
        wrow[k] = valid ? wv : 0.f;
      }
      wrow[15] = 0.f;
    }
    // all 64 lanes: lane handles feature channels (2l, 2l+1)
    float acc0[KKP], acc1[KKP];
#pragma unroll
    for (int k = 0; k < KKP; k++) { acc0[k] = 0.f; acc1[k] = 0.f; }
#pragma unroll 4
    for (int n = 0; n < NNB; n++) {
      unsigned int off = nb[w*32 + n];
      unsigned int xu = *(const unsigned int*)((const char*)featbf + off + l*4);
      float x0 = bf2f(xu & 0xffffu);
      float x1 = bf2f(xu >> 16);
      const float4* wr4 = (const float4*)(wl + (w*32 + n) * 16);
      float4 wa = wr4[0], wb = wr4[1], wc = wr4[2], wd = wr4[3];
      float wk[16] = {wa.x,wa.y,wa.z,wa.w, wb.x,wb.y,wb.z,wb.w,
                      wc.x,wc.y,wc.z,wc.w, wd.x,wd.y,wd.z,wd.w};
#pragma unroll
      for (int k = 0; k < KKP; k++) { acc0[k] += wk[k]*x0; acc1[k] += wk[k]*x1; }
    }
    // write wfeat row s, bf16, XOR-swizzled (row stride 3840B is bank-aligned)
    char* rowp = (char*)wf + s * 3840;
    int swz = (s & 7) << 4;
#pragma unroll
    for (int k = 0; k < KKP; k++) {
      unsigned int pk2 = f2bf(acc0[k]) | (f2bf(acc1[k]) << 16);
      *(unsigned int*)(rowp + ((k*256 + l*4) ^ swz)) = pk2;
    }
  }
  __syncthreads();

  // ---- conv GEMM: C[32][128] = wf[32][1920] x kpw[1920][128] via MFMA bf16 ----
  const int mt = w >> 1, oh = w & 1;
  const int lr = l & 15, lg = l >> 4;
  const int mrow = mt*16 + lr;
  const char* arow = (const char*)wf + (size_t)mrow * 3840;
  const int aswz = (mrow & 7) << 4;
  const char* bbase = (const char*)kpwT + (size_t)(oh*64 + lr) * (KCDIM*2) + lg*16;

  f32x4 c0 = {0,0,0,0}, c1 = {0,0,0,0}, c2v = {0,0,0,0}, c3 = {0,0,0,0};
#pragma unroll 4
  for (int step = 0; step < 60; step++) {
    bf16x8 a = *(const bf16x8*)(arow + ((step*64 + lg*16) ^ aswz));
    bf16x8 b0 = *(const bf16x8*)(bbase + (size_t)0*16*KCDIM*2 + step*64);
    bf16x8 b1 = *(const bf16x8*)(bbase + (size_t)1*16*KCDIM*2 + step*64);
    bf16x8 b2 = *(const bf16x8*)(bbase + (size_t)2*16*KCDIM*2 + step*64);
    bf16x8 b3 = *(const bf16x8*)(bbase + (size_t)3*16*KCDIM*2 + step*64);
    c0  = __builtin_amdgcn_mfma_f32_16x16x32_bf16(a, b0, c0, 0,0,0);
    c1  = __builtin_amdgcn_mfma_f32_16x16x32_bf16(a, b1, c1, 0,0,0);
    c2v = __builtin_amdgcn_mfma_f32_16x16x32_bf16(a, b2, c2v, 0,0,0);
    c3  = __builtin_amdgcn_mfma_f32_16x16x32_bf16(a, b3, c3, 0,0,0);
  }

  // a2 = leaky(conv) bf16, swizzled (C/D layout: col=lane&15, row=(lane>>4)*4+reg)
#define WRITE_A2_67723(CV, OT) { \
  _Pragma("unroll") for (int r = 0; r < 4; r++) { \
    float v = leaky(CV[r]); \
    int m = mt*16 + lg*4 + r; \
    int o = oh*64 + (OT)*16 + lr; \
    *(unsigned short*)(a2 + m*256 + ((o*2) ^ ((m & 7) << 4))) = (unsigned short)f2bf(v); \
  } }
  WRITE_A2_67723(c0, 0) WRITE_A2_67723(c1, 1) WRITE_A2_67723(c2v, 2) WRITE_A2_67723(c3, 3)
  __syncthreads();

  // ---- post + shortcut GEMMs, biases folded into C init ----
  int obase = oh*64 + lr;
  float bias0 = bpost[obase+ 0] + bsc[obase+ 0];
  float bias1 = bpost[obase+16] + bsc[obase+16];
  float bias2 = bpost[obase+32] + bsc[obase+32];
  float bias3 = bpost[obase+48] + bsc[obase+48];
  f32x4 d0 = {bias0,bias0,bias0,bias0};
  f32x4 d1 = {bias1,bias1,bias1,bias1};
  f32x4 d2 = {bias2,bias2,bias2,bias2};
  f32x4 d3 = {bias3,bias3,bias3,bias3};

  const char* a2row = a2 + (size_t)mrow * 256;
  const char* wpb = (const char*)wpostT + (size_t)obase * 256 + lg*16;
#pragma unroll
  for (int step = 0; step < 4; step++) {
    bf16x8 a = *(const bf16x8*)(a2row + ((step*64 + lg*16) ^ aswz));
    bf16x8 b0 = *(const bf16x8*)(wpb + 0*16*256 + step*64);
    bf16x8 b1 = *(const bf16x8*)(wpb + 1*16*256 + step*64);
    bf16x8 b2 = *(const bf16x8*)(wpb + 2*16*256 + step*64);
    bf16x8 b3 = *(const bf16x8*)(wpb + 3*16*256 + step*64);
    d0 = __builtin_amdgcn_mfma_f32_16x16x32_bf16(a, b0, d0, 0,0,0);
    d1 = __builtin_amdgcn_mfma_f32_16x16x32_bf16(a, b1, d1, 0,0,0);
    d2 = __builtin_amdgcn_mfma_f32_16x16x32_bf16(a, b2, d2, 0,0,0);
    d3 = __builtin_amdgcn_mfma_f32_16x16x32_bf16(a, b3, d3, 0,0,0);
  }
  const char* a3row = a3 + (size_t)mrow * 128;
  const char* wsb = (const char*)wscT + (size_t)obase * 128 + lg*16;
#pragma unroll
  for (int step = 0; step < 2; step++) {
    bf16x8 a = *(const bf16x8*)(a3row + ((step*64 + lg*16) ^ aswz));
    bf16x8 b0 = *(const bf16x8*)(wsb + 0*16*128 + step*64);
    bf16x8 b1 = *(const bf16x8*)(wsb + 1*16*128 + step*64);
    bf16x8 b2 = *(const bf16x8*)(wsb + 2*16*128 + step*64);
    bf16x8 b3 = *(const bf16x8*)(wsb + 3*16*128 + step*64);
    d0 = __builtin_amdgcn_mfma_f32_16x16x32_bf16(a, b0, d0, 0,0,0);
    d1 = __builtin_amdgcn_mfma_f32_16x16x32_bf16(a, b1, d1, 0,0,0);
    d2 = __builtin_amdgcn_mfma_f32_16x16x32_bf16(a, b2, d2, 0,0,0);
    d3 = __builtin_amdgcn_mfma_f32_16x16x32_bf16(a, b3, d3, 0,0,0);
  }

#define STORE_OUT_67723(DV, OT) { \
  _Pragma("unroll") for (int r = 0; r < 4; r++) { \
    int m = mt*16 + lg*4 + r; \
    int o = oh*64 + (OT)*16 + lr; \
    out[(size_t)(m0 + m)*OUTF + o] = leaky(DV[r]); \
  } }
  STORE_OUT_67723(d0, 0) STORE_OUT_67723(d1, 1) STORE_OUT_67723(d2, 2) STORE_OUT_67723(d3, 3)
}

extern "C" void kernel_launch(void* const* d_in, const int* in_sizes, int n_in,
                              void* d_out, int out_size, void* d_ws, size_t ws_size,
                              hipStream_t stream)
{
  const float* points   = (const float*)d_in[0];
  const float* features = (const float*)d_in[1];
  const float* W_pre    = (const float*)d_in[2];
  const float* b_pre    = (const float*)d_in[3];
  const float* kpts     = (const float*)d_in[4];
  const float* kpw      = (const float*)d_in[5];
  const float* W_post   = (const float*)d_in[6];
  const float* b_post   = (const float*)d_in[7];
  const float* W_sc     = (const float*)d_in[8];
  const float* b_sc     = (const float*)d_in[9];
  const int* sample_idx = (const int*)d_in[10];
  const int* nbr        = (const int*)d_in[11];
  float* out = (float*)d_out;

  char* ws = (char*)d_ws;
  unsigned short* featbf = (unsigned short*)ws;                 // 33,554,432 B
  unsigned short* kpwT   = (unsigned short*)(ws + 33554432);    //    491,520 B
  unsigned short* wpostT = (unsigned short*)(ws + 34045952);    //     32,768 B
  unsigned short* wscT   = (unsigned short*)(ws + 34078720);    //     16,384 B

  double ext = (1.5 / 40.0) / (pow(15.0, 1.0 / 3.0) - 1.0) * 1.5;
  float inv_ext = (float)(1.0 / ext);

  // allow >64KB dynamic LDS (no-op if unsupported on this ROCm)
  (void)hipFuncSetAttribute((const void*)k_fused_67723,
                            hipFuncAttributeMaxDynamicSharedMemorySize, 143872);

  k_cvt_67723<<<1056, 256, 0, stream>>>(kpw, W_post, W_sc, kpwT, wpostT, wscT);
  k_pre_67723<<<4096, 256, 0, stream>>>(features, W_pre, b_pre, featbf);
  k_fused_67723<<<2048, 256, 143872, stream>>>(points, features, kpts, b_post, b_sc,
                                               sample_idx, nbr, featbf, kpwT, wpostT,
                                               wscT, out, inv_ext);
}

// Round 2
// 200.299 us; speedup vs baseline: 4.3002x; 4.3002x over previous
//
#include <hip/hip_runtime.h>
#include <cmath>

#define NPTS 131072
#define MTOT 65536
#define NNB  32
#define KKP  15
#define INF  64
#define OUTF 128
#define KCDIM 1920
#define ROWB 3840   // bytes per wfeat/kpwT row (1920 * 2B)

typedef __attribute__((ext_vector_type(8))) __bf16 bf16x8;
typedef __attribute__((ext_vector_type(8))) unsigned short u16x8;
typedef __attribute__((ext_vector_type(4))) float f32x4;
typedef unsigned int u32;

__device__ __forceinline__ float bf2f(u32 v){ return __builtin_bit_cast(float, v<<16); }
__device__ __forceinline__ u32 f2bf(float f){
  u32 u = __builtin_bit_cast(u32, f);
  return (u + 0x7fffu + ((u>>16)&1u)) >> 16;
}
__device__ __forceinline__ float leaky(float v){ return v >= 0.f ? v : 0.01f*v; }

__device__ __forceinline__ void g2l16(const void* g, void* l){
  __builtin_amdgcn_global_load_lds((const __attribute__((address_space(1))) u32*)g,
                                   (__attribute__((address_space(3))) u32*)l, 16, 0, 0);
}

// ---------------- K0: weight transpose + bf16 convert ----------------
__global__ __launch_bounds__(256) void k_cvt_67723(
    const float* __restrict__ kpw, const float* __restrict__ wpost,
    const float* __restrict__ wsc, const float* __restrict__ wpre,
    unsigned short* __restrict__ kpwT, unsigned short* __restrict__ wpostT,
    unsigned short* __restrict__ wscT, unsigned short* __restrict__ wpreT)
{
  int tid = blockIdx.x * 256 + threadIdx.x;
  if (tid < OUTF * KCDIM) {                       // kpwT[o][kc] = kpw[kc*128+o]
    int o = tid / KCDIM, kc = tid % KCDIM;
    kpwT[tid] = (unsigned short)f2bf(kpw[(size_t)kc * OUTF + o]);
    return;
  }
  int t2 = tid - OUTF * KCDIM;
  if (t2 < OUTF * OUTF) {                         // wpostT[out][in]
    int o = t2 / OUTF, i = t2 % OUTF;
    wpostT[t2] = (unsigned short)f2bf(wpost[i * OUTF + o]);
    return;
  }
  int t3 = t2 - OUTF * OUTF;
  if (t3 < OUTF * INF) {                          // wscT[out][in]
    int o = t3 / INF, c = t3 % INF;
    wscT[t3] = (unsigned short)f2bf(wsc[c * OUTF + o]);
    return;
  }
  int t4 = t3 - OUTF * INF;
  if (t4 < OUTF * INF) {                          // wpreT[out][in]
    int o = t4 / INF, c = t4 % INF;
    wpreT[t4] = (unsigned short)f2bf(wpre[c * OUTF + o]);
  }
}

// ---------------- K1: pre layer via MFMA: featbf = leaky(features @ W_pre + b) ----
__global__ __launch_bounds__(256) void k_pre_67723(
    const float* __restrict__ feat, const unsigned short* __restrict__ wpreT,
    const float* __restrict__ bp, unsigned short* __restrict__ featbf)
{
  const int w = threadIdx.x >> 6, l = threadIdx.x & 63, lr = l & 15, lg = l >> 4;
  const int m0 = blockIdx.x * 128 + w * 32;
  f32x4 acc[2][8];
#pragma unroll
  for (int ot = 0; ot < 8; ot++) {
    float bv = bp[ot*16 + lr];
    f32x4 s = {bv, bv, bv, bv};
    acc[0][ot] = s; acc[1][ot] = s;
  }
  bf16x8 af[2][2];
#pragma unroll
  for (int mi = 0; mi < 2; mi++)
#pragma unroll
  for (int ks = 0; ks < 2; ks++) {
    const float* src = feat + (size_t)(m0 + mi*16 + lr) * INF + ks*32 + lg*8;
    float4 f0 = *(const float4*)src, f1 = *(const float4*)(src + 4);
    u16x8 p;
    p[0]=f2bf(f0.x); p[1]=f2bf(f0.y); p[2]=f2bf(f0.z); p[3]=f2bf(f0.w);
    p[4]=f2bf(f1.x); p[5]=f2bf(f1.y); p[6]=f2bf(f1.z); p[7]=f2bf(f1.w);
    af[mi][ks] = __builtin_bit_cast(bf16x8, p);
  }
#pragma unroll
  for (int ks = 0; ks < 2; ks++)
#pragma unroll
  for (int ot = 0; ot < 8; ot++) {
    bf16x8 b = *(const bf16x8*)(wpreT + (size_t)(ot*16 + lr) * INF + ks*32 + lg*8);
    acc[0][ot] = __builtin_amdgcn_mfma_f32_16x16x32_bf16(af[0][ks], b, acc[0][ot], 0,0,0);
    acc[1][ot] = __builtin_amdgcn_mfma_f32_16x16x32_bf16(af[1][ks], b, acc[1][ot], 0,0,0);
  }
#pragma unroll
  for (int mi = 0; mi < 2; mi++)
#pragma unroll
  for (int ot = 0; ot < 8; ot++)
#pragma unroll
  for (int r = 0; r < 4; r++) {
    int m = m0 + mi*16 + lg*4 + r;
    featbf[(size_t)m * OUTF + ot*16 + lr] = (unsigned short)f2bf(leaky(acc[mi][ot][r]));
  }
}

// ---------------- K2a: wfeat[m][k*128+c] = sum_n w[m,n,k] * featbf[nbr[m,n]][c] ----
// No LDS. Per wave: 2 samples; weights live in lanes (0-31 -> sample A, 32-63 -> B),
// broadcast via v_readlane; all 64 lanes accumulate 2 channels each.
__global__ __launch_bounds__(256) void k_wfeat_67723(
    const float* __restrict__ points, const float* __restrict__ kp,
    const int* __restrict__ sample_idx, const int* __restrict__ nbr,
    const unsigned short* __restrict__ featbf, unsigned short* __restrict__ wfeat,
    float inv_ext, int mbase)
{
  const int w = threadIdx.x >> 6, l = threadIdx.x & 63;
  const int s2 = (blockIdx.x * 4 + w) * 2;          // chunk-local sample pair base
  const int half = l >> 5, n_ = l & 31;
  const int gm = mbase + s2 + half;
  const int sidx = sample_idx[gm];
  const float qx = points[sidx*3+0], qy = points[sidx*3+1], qz = points[sidx*3+2];
  const int ni = nbr[(size_t)gm * NNB + n_];
  const bool valid = ni < NPTS;
  const int nic = valid ? ni : 0;
  const u32 nboff = (u32)nic * (OUTF * 2);
  const float px = points[nic*3+0], py = points[nic*3+1], pz = points[nic*3+2];
  const float dx = px - qx, dy = py - qy, dz = pz - qz;
  float wk[KKP];
#pragma unroll
  for (int k = 0; k < KKP; k++) {
    float ex = dx - kp[k*3+0], ey = dy - kp[k*3+1], ez = dz - kp[k*3+2];
    float d = sqrtf(ex*ex + ey*ey + ez*ez);
    float wv = fmaxf(1.f - d * inv_ext, 0.f);
    wk[k] = valid ? wv : 0.f;
  }
  // neighbors are nearest-first with shadow padding at the end -> prefix is valid
  unsigned long long bal = __ballot(valid);
  const int cA = __popcll(bal & 0xffffffffull);
  const int cB = __popcll(bal >> 32);
  const char* fb = (const char*)featbf;
#pragma unroll
  for (int h2 = 0; h2 < 2; h2++) {
    const int cnt = h2 ? cB : cA;
    float a0[KKP], a1[KKP];
#pragma unroll
    for (int k = 0; k < KKP; k++) { a0[k] = 0.f; a1[k] = 0.f; }
#pragma unroll
    for (int n = 0; n < NNB; n++) {
      if (n >= cnt) break;                          // uniform (SGPR) branch
      u32 off = (u32)__builtin_amdgcn_readlane((int)nboff, h2*32 + n);
      u32 xu = *(const u32*)(fb + off + l*4);       // 2 bf16 channels per lane
      float x0 = bf2f(xu & 0xffffu), x1 = bf2f(xu >> 16);
#pragma unroll
      for (int k = 0; k < KKP; k++) {
        float wv = __builtin_bit_cast(float,
            __builtin_amdgcn_readlane(__builtin_bit_cast(int, wk[k]), h2*32 + n));
        a0[k] = fmaf(wv, x0, a0[k]);
        a1[k] = fmaf(wv, x1, a1[k]);
      }
    }
    u32* drow = (u32*)(wfeat + (size_t)(s2 + h2) * KCDIM);
#pragma unroll
    for (int k = 0; k < KKP; k++)
      drow[k*64 + l] = f2bf(a0[k]) | (f2bf(a1[k]) << 16);
  }
}

// ---------------- K2b: conv GEMM [128 x 1920]x[1920 x 128] + post + shortcut ----
// 256 thr / 4 waves, wave owns 32 rows x 128 cols. BK=64, dbuf LDS via
// global_load_lds (linear dest + inverse-swizzled source + swizzled ds_read).
__global__ __launch_bounds__(256) void k_conv_67723(
    const unsigned short* __restrict__ wfeat, const unsigned short* __restrict__ kpwT,
    const unsigned short* __restrict__ wpostT, const unsigned short* __restrict__ wscT,
    const float* __restrict__ features, const float* __restrict__ bpost,
    const float* __restrict__ bsc, const int* __restrict__ sample_idx,
    float* __restrict__ out, int mbase)
{
  extern __shared__ char smem[];
  const int t = threadIdx.x, w = t >> 6, l = t & 63, lr = l & 15, lg = l >> 4;
  const int m0 = blockIdx.x * 128;                  // chunk-local row base

  f32x4 acc[2][8];
#pragma unroll
  for (int mi = 0; mi < 2; mi++)
#pragma unroll
  for (int ot = 0; ot < 8; ot++) acc[mi][ot] = (f32x4){0,0,0,0};

  const char* arows = (const char*)wfeat + (size_t)m0 * ROWB;
  const char* brows = (const char*)kpwT;
  const int qbase = w * 4;
  const int srow = l >> 3;                          // row within 8-row group
  const int sinner = ((l & 7) * 16) ^ (srow << 4);  // inverse-swizzled source offset

  // stage kt = 0 into buffer 0
#pragma unroll
  for (int j = 0; j < 4; j++) {
    int q = qbase + j; int m = q*8 + srow;
    g2l16(arows + (size_t)m * ROWB + sinner, smem + q*1024);
    g2l16(brows + (size_t)m * ROWB + sinner, smem + 16384 + q*1024);
  }
  __syncthreads();

  for (int kt = 0; kt < 30; kt++) {
    const int cur = kt & 1;
    const int nxt_off = (cur ^ 1) << 15;            // 0 or 32768
    if (kt < 29) {
      const int kb = (kt + 1) * 128;
#pragma unroll
      for (int j = 0; j < 4; j++) {
        int q = qbase + j; int m = q*8 + srow;
        g2l16(arows + (size_t)m * ROWB + kb + sinner, smem + nxt_off + q*1024);
        g2l16(brows + (size_t)m * ROWB + kb + sinner, smem + nxt_off + 16384 + q*1024);
      }
    }
    const char* Ab = smem + (cur << 15);
    const char* Bb = Ab + 16384;
#pragma unroll
    for (int ks = 0; ks < 2; ks++) {
      bf16x8 af[2];
#pragma unroll
      for (int mi = 0; mi < 2; mi++) {
        int m = (w*2 + mi)*16 + lr;
        af[mi] = *(const bf16x8*)(Ab + m*128 + ((ks*64 + lg*16) ^ ((m & 7) << 4)));
      }
#pragma unroll
      for (int ot = 0; ot < 8; ot++) {
        int o = ot*16 + lr;
        bf16x8 bfr = *(const bf16x8*)(Bb + o*128 + ((ks*64 + lg*16) ^ ((o & 7) << 4)));
        acc[0][ot] = __builtin_amdgcn_mfma_f32_16x16x32_bf16(af[0], bfr, acc[0][ot], 0,0,0);
        acc[1][ot] = __builtin_amdgcn_mfma_f32_16x16x32_bf16(af[1], bfr, acc[1][ot], 0,0,0);
      }
    }
    __syncthreads();
  }

  // ---- epilogue staging: a2 = leaky(conv) bf16 [128][256B swz]; a3 = raw feats [128][128B swz]
  char* a2 = smem;                                   // 32 KB (old buffer 0)
  char* a3 = smem + 32768;                           // 16 KB (old A1)
#pragma unroll
  for (int mi = 0; mi < 2; mi++)
#pragma unroll
  for (int ot = 0; ot < 8; ot++)
#pragma unroll
  for (int r = 0; r < 4; r++) {
    int m = (w*2 + mi)*16 + lg*4 + r;
    int o = ot*16 + lr;
    *(unsigned short*)(a2 + m*256 + ((o*2) ^ ((m & 15) << 4))) =
        (unsigned short)f2bf(leaky(acc[mi][ot][r]));
  }
  {
    int r = t >> 1, h = t & 1;
    int sidx = sample_idx[mbase + m0 + r];
    const float* src = features + (size_t)sidx * INF + h*32;
#pragma unroll
    for (int qq = 0; qq < 4; qq++) {
      float4 f0 = *(const float4*)(src + qq*8);
      float4 f1 = *(const float4*)(src + qq*8 + 4);
      uint4 pv = make_uint4(f2bf(f0.x) | (f2bf(f0.y) << 16),
                            f2bf(f0.z) | (f2bf(f0.w) << 16),
                            f2bf(f1.x) | (f2bf(f1.y) << 16),
                            f2bf(f1.z) | (f2bf(f1.w) << 16));
      *(uint4*)(a3 + r*128 + ((h*64 + qq*16) ^ ((r & 7) << 4))) = pv;
    }
  }
  __syncthreads();

  // ---- post (K=128) + shortcut (K=64), biases folded into C init ----
  f32x4 d[2][8];
#pragma unroll
  for (int ot = 0; ot < 8; ot++) {
    float bv = bpost[ot*16 + lr] + bsc[ot*16 + lr];
    f32x4 s = {bv, bv, bv, bv};
    d[0][ot] = s; d[1][ot] = s;
  }
#pragma unroll
  for (int st = 0; st < 4; st++) {
    bf16x8 af[2];
#pragma unroll
    for (int mi = 0; mi < 2; mi++) {
      int m = (w*2 + mi)*16 + lr;
      af[mi] = *(const bf16x8*)(a2 + m*256 + ((st*64 + lg*16) ^ ((m & 15) << 4)));
    }
#pragma unroll
    for (int ot = 0; ot < 8; ot++) {
      bf16x8 b = *(const bf16x8*)(wpostT + (size_t)(ot*16 + lr) * OUTF + st*32 + lg*8);
      d[0][ot] = __builtin_amdgcn_mfma_f32_16x16x32_bf16(af[0], b, d[0][ot], 0,0,0);
      d[1][ot] = __builtin_amdgcn_mfma_f32_16x16x32_bf16(af[1], b, d[1][ot], 0,0,0);
    }
  }
#pragma unroll
  for (int st = 0; st < 2; st++) {
    bf16x8 af[2];
#pragma unroll
    for (int mi = 0; mi < 2; mi++) {
      int m = (w*2 + mi)*16 + lr;
      af[mi] = *(const bf16x8*)(a3 + m*128 + ((st*64 + lg*16) ^ ((m & 7) << 4)));
    }
#pragma unroll
    for (int ot = 0; ot < 8; ot++) {
      bf16x8 b = *(const bf16x8*)(wscT + (size_t)(ot*16 + lr) * INF + st*32 + lg*8);
      d[0][ot] = __builtin_amdgcn_mfma_f32_16x16x32_bf16(af[0], b, d[0][ot], 0,0,0);
      d[1][ot] = __builtin_amdgcn_mfma_f32_16x16x32_bf16(af[1], b, d[1][ot], 0,0,0);
    }
  }
#pragma unroll
  for (int mi = 0; mi < 2; mi++)
#pragma unroll
  for (int ot = 0; ot < 8; ot++)
#pragma unroll
  for (int r = 0; r < 4; r++) {
    int m = (w*2 + mi)*16 + lg*4 + r;
    out[(size_t)(mbase + m0 + m) * OUTF + ot*16 + lr] = leaky(d[mi][ot][r]);
  }
}

extern "C" void kernel_launch(void* const* d_in, const int* in_sizes, int n_in,
                              void* d_out, int out_size, void* d_ws, size_t ws_size,
                              hipStream_t stream)
{
  const float* points   = (const float*)d_in[0];
  const float* features = (const float*)d_in[1];
  const float* W_pre    = (const float*)d_in[2];
  const float* b_pre    = (const float*)d_in[3];
  const float* kpts     = (const float*)d_in[4];
  const float* kpw      = (const float*)d_in[5];
  const float* W_post   = (const float*)d_in[6];
  const float* b_post   = (const float*)d_in[7];
  const float* W_sc     = (const float*)d_in[8];
  const float* b_sc     = (const float*)d_in[9];
  const int* sample_idx = (const int*)d_in[10];
  const int* nbr        = (const int*)d_in[11];
  float* out = (float*)d_out;

  char* ws = (char*)d_ws;
  unsigned short* featbf = (unsigned short*)ws;                 // 33,554,432 B
  unsigned short* kpwT   = (unsigned short*)(ws + 33554432);    //    491,520 B
  unsigned short* wpostT = (unsigned short*)(ws + 34045952);    //     32,768 B
  unsigned short* wscT   = (unsigned short*)(ws + 34078720);    //     16,384 B
  unsigned short* wpreT  = (unsigned short*)(ws + 34095104);    //     16,384 B
  unsigned short* wfeat  = (unsigned short*)(ws + 34111488);    // up to 240 MB

  double ext = (1.5 / 40.0) / (pow(15.0, 1.0 / 3.0) - 1.0) * 1.5;
  float inv_ext = (float)(1.0 / ext);

  // chunk wfeat if workspace is small (deterministic in ws_size)
  size_t fixed = 34111488ull;
  int chunks = 1;
  while (chunks < 32 && fixed + 251658240ull / (size_t)chunks > ws_size) chunks <<= 1;
  int msz = MTOT / chunks;

  (void)hipFuncSetAttribute((const void*)k_conv_67723,
                            hipFuncAttributeMaxDynamicSharedMemorySize, 65536);

  k_cvt_67723<<<1088, 256, 0, stream>>>(kpw, W_post, W_sc, W_pre, kpwT, wpostT, wscT, wpreT);
  k_pre_67723<<<1024, 256, 0, stream>>>(features, wpreT, b_pre, featbf);
  for (int ci = 0; ci < chunks; ci++) {
    k_wfeat_67723<<<msz/8, 256, 0, stream>>>(points, kpts, sample_idx, nbr, featbf,
                                             wfeat, inv_ext, ci*msz);
    k_conv_67723<<<msz/128, 256, 65536, stream>>>(wfeat, kpwT, wpostT, wscT, features,
                                                  b_post, b_sc, sample_idx, out, ci*msz);
  }
}

// Round 3
// 167.543 us; speedup vs baseline: 5.1409x; 1.1955x over previous
//
#include <hip/hip_runtime.h>
#include <cmath>

#define NPTS 131072
#define MTOT 65536
#define NNB  32
#define KKP  15
#define INF  64
#define OUTF 128
#define KCDIM 1920
#define ROWB 3840   // bytes per wfeat/kpwT row (1920 * 2B)

typedef __attribute__((ext_vector_type(8))) __bf16 bf16x8;
typedef __attribute__((ext_vector_type(8))) unsigned short u16x8;
typedef __attribute__((ext_vector_type(4))) float f32x4;
typedef unsigned int u32;

__device__ __forceinline__ float bf2f(u32 v){ return __builtin_bit_cast(float, v<<16); }
__device__ __forceinline__ u32 f2bf(float f){
  u32 u = __builtin_bit_cast(u32, f);
  return (u + 0x7fffu + ((u>>16)&1u)) >> 16;
}
__device__ __forceinline__ float leaky(float v){ return v >= 0.f ? v : 0.01f*v; }

__device__ __forceinline__ void g2l16(const void* g, void* l){
  __builtin_amdgcn_global_load_lds((const __attribute__((address_space(1))) u32*)g,
                                   (__attribute__((address_space(3))) u32*)l, 16, 0, 0);
}

// ---------------- K0: weight transpose + bf16 convert ----------------
__global__ __launch_bounds__(256) void k_cvt_67723(
    const float* __restrict__ kpw, const float* __restrict__ wpost,
    const float* __restrict__ wsc, const float* __restrict__ wpre,
    unsigned short* __restrict__ kpwT, unsigned short* __restrict__ wpostT,
    unsigned short* __restrict__ wscT, unsigned short* __restrict__ wpreT)
{
  int tid = blockIdx.x * 256 + threadIdx.x;
  if (tid < OUTF * KCDIM) {                       // kpwT[o][kc] = kpw[kc*128+o]
    int o = tid / KCDIM, kc = tid % KCDIM;
    kpwT[tid] = (unsigned short)f2bf(kpw[(size_t)kc * OUTF + o]);
    return;
  }
  int t2 = tid - OUTF * KCDIM;
  if (t2 < OUTF * OUTF) {                         // wpostT[out][in]
    int o = t2 / OUTF, i = t2 % OUTF;
    wpostT[t2] = (unsigned short)f2bf(wpost[i * OUTF + o]);
    return;
  }
  int t3 = t2 - OUTF * OUTF;
  if (t3 < OUTF * INF) {                          // wscT[out][in]
    int o = t3 / INF, c = t3 % INF;
    wscT[t3] = (unsigned short)f2bf(wsc[c * OUTF + o]);
    return;
  }
  int t4 = t3 - OUTF * INF;
  if (t4 < OUTF * INF) {                          // wpreT[out][in]
    int o = t4 / INF, c = t4 % INF;
    wpreT[t4] = (unsigned short)f2bf(wpre[c * OUTF + o]);
  }
}

// ---------------- K1: pre layer via MFMA: featbf = leaky(features @ W_pre + b) ----
__global__ __launch_bounds__(256) void k_pre_67723(
    const float* __restrict__ feat, const unsigned short* __restrict__ wpreT,
    const float* __restrict__ bp, unsigned short* __restrict__ featbf)
{
  const int w = threadIdx.x >> 6, l = threadIdx.x & 63, lr = l & 15, lg = l >> 4;
  const int m0 = blockIdx.x * 128 + w * 32;
  f32x4 acc[2][8];
#pragma unroll
  for (int ot = 0; ot < 8; ot++) {
    float bv = bp[ot*16 + lr];
    f32x4 s = {bv, bv, bv, bv};
    acc[0][ot] = s; acc[1][ot] = s;
  }
  bf16x8 af[2][2];
#pragma unroll
  for (int mi = 0; mi < 2; mi++)
#pragma unroll
  for (int ks = 0; ks < 2; ks++) {
    const float* src = feat + (size_t)(m0 + mi*16 + lr) * INF + ks*32 + lg*8;
    float4 f0 = *(const float4*)src, f1 = *(const float4*)(src + 4);
    u16x8 p;
    p[0]=f2bf(f0.x); p[1]=f2bf(f0.y); p[2]=f2bf(f0.z); p[3]=f2bf(f0.w);
    p[4]=f2bf(f1.x); p[5]=f2bf(f1.y); p[6]=f2bf(f1.z); p[7]=f2bf(f1.w);
    af[mi][ks] = __builtin_bit_cast(bf16x8, p);
  }
#pragma unroll
  for (int ks = 0; ks < 2; ks++)
#pragma unroll
  for (int ot = 0; ot < 8; ot++) {
    bf16x8 b = *(const bf16x8*)(wpreT + (size_t)(ot*16 + lr) * INF + ks*32 + lg*8);
    acc[0][ot] = __builtin_amdgcn_mfma_f32_16x16x32_bf16(af[0][ks], b, acc[0][ot], 0,0,0);
    acc[1][ot] = __builtin_amdgcn_mfma_f32_16x16x32_bf16(af[1][ks], b, acc[1][ot], 0,0,0);
  }
#pragma unroll
  for (int mi = 0; mi < 2; mi++)
#pragma unroll
  for (int ot = 0; ot < 8; ot++)
#pragma unroll
  for (int r = 0; r < 4; r++) {
    int m = m0 + mi*16 + lg*4 + r;
    featbf[(size_t)m * OUTF + ot*16 + lr] = (unsigned short)f2bf(leaky(acc[mi][ot][r]));
  }
}

// ---------------- K2a: wfeat via MFMA ----------------
// Per sample: wfeat[16k x 128c] = w^T[16k x 32n] @ X[32n x 128c], one wave per
// sample-step, 8 mfma_16x16x32. B-frags gathered straight from global featbf
// (16-lane groups read consecutive channels of one neighbor -> coalesced).
__global__ __launch_bounds__(256) void k_wfmma_67723(
    const float* __restrict__ points, const float* __restrict__ kp,
    const int* __restrict__ sample_idx, const int* __restrict__ nbr,
    const unsigned short* __restrict__ featbf, unsigned short* __restrict__ wfeat,
    float inv_ext, int mbase, int nwg)
{
  __shared__ float4 meta[16][32];
  const int bid = blockIdx.x;
  const int swb = (bid & 7) * (nwg >> 3) + (bid >> 3);   // XCD-contiguous swizzle
  const int m0l = swb * 16;                               // chunk-local sample base
  const int gm0 = mbase + m0l;
  const int t = threadIdx.x;

  // phase 0: neighbor meta (dx,dy,dz, feat-row byte offset); invalid -> dx=1e9
  for (int e = t; e < 512; e += 256) {
    int s = e >> 5, n = e & 31;
    int gm = gm0 + s;
    int sidx = sample_idx[gm];
    int ni = nbr[(size_t)gm * NNB + n];
    bool valid = ni < NPTS;
    int nic = valid ? ni : 0;
    float qx = points[sidx*3], qy = points[sidx*3+1], qz = points[sidx*3+2];
    float dx = points[nic*3] - qx, dy = points[nic*3+1] - qy, dz = points[nic*3+2] - qz;
    if (!valid) dx = 1e9f;
    meta[s][n] = make_float4(dx, dy, dz, __int_as_float(nic * (OUTF*2)));
  }
  __syncthreads();

  const int l = t & 63, w = t >> 6, lr = l & 15, lg = l >> 4;
  const bool kvalid = lr < KKP;
  const int kk = kvalid ? lr : 0;
  const float kx = kp[kk*3], ky = kp[kk*3+1], kz = kp[kk*3+2];
  const char* fb = (const char*)featbf;
  const f32x4 zero = {0,0,0,0};

  for (int i = 0; i < 4; i++) {
    const int s = w*4 + i;
    float4 mj[8];
#pragma unroll
    for (int j = 0; j < 8; j++) mj[j] = meta[s][lg*8 + j];

    // A-frag: w[k=lr][n=lg*8+j], j = K-slot order (must match B slots)
    u32 apk[4];
#pragma unroll
    for (int j2 = 0; j2 < 4; j2++) {
      u32 lohi[2];
#pragma unroll
      for (int h = 0; h < 2; h++) {
        float4 m_ = mj[2*j2 + h];
        float ex = m_.x - kx, ey = m_.y - ky, ez = m_.z - kz;
        float d = sqrtf(ex*ex + ey*ey + ez*ez);
        float wv = fmaxf(1.f - d * inv_ext, 0.f);
        lohi[h] = kvalid ? f2bf(wv) : 0u;
      }
      apk[j2] = lohi[0] | (lohi[1] << 16);
    }
    bf16x8 afr = __builtin_bit_cast(bf16x8, apk);

#pragma unroll
    for (int t2 = 0; t2 < 2; t2++) {
      // gather: neighbor (lg*8+j), channels [t2*64 + 4*lr, +4)
      uint2 dj[8];
#pragma unroll
      for (int j = 0; j < 8; j++) {
        u32 off = __builtin_bit_cast(u32, mj[j].w);
        dj[j] = *(const uint2*)(fb + off + t2*128 + lr*8);
      }
      f32x4 D[4];
#pragma unroll
      for (int q = 0; q < 4; q++) {
        u32 b[4];
#pragma unroll
        for (int u = 0; u < 4; u++) {
          u32 w0 = (q < 2) ? dj[2*u].x   : dj[2*u].y;
          u32 w1 = (q < 2) ? dj[2*u+1].x : dj[2*u+1].y;
          b[u] = __builtin_amdgcn_perm(w1, w0, (q & 1) ? 0x07060302u : 0x05040100u);
        }
        D[q] = __builtin_amdgcn_mfma_f32_16x16x32_bf16(
                   afr, __builtin_bit_cast(bf16x8, b), zero, 0,0,0);
      }
      // D[q] col lr -> channel t2*64 + 4*lr + q; rows k = lg*4 + r (skip k=15)
#pragma unroll
      for (int r = 0; r < 4; r++) {
        int kr = lg*4 + r;
        if (kr < KKP) {
          uint2 pv;
          pv.x = f2bf(D[0][r]) | (f2bf(D[1][r]) << 16);
          pv.y = f2bf(D[2][r]) | (f2bf(D[3][r]) << 16);
          *(uint2*)((char*)wfeat + (size_t)(m0l + s) * ROWB + kr*256 + t2*128 + lr*8) = pv;
        }
      }
    }
  }
}

// ---------------- K2b: conv GEMM [128 x 1920]x[1920 x 128] + post + shortcut ----
// 512 thr / 8 waves; wave = 32m x 64o. BK=64 dbuf LDS via global_load_lds
// (linear dest + inverse-swizzled source + swizzled ds_read).
__global__ __launch_bounds__(512) void k_conv_67723(
    const unsigned short* __restrict__ wfeat, const unsigned short* __restrict__ kpwT,
    const unsigned short* __restrict__ wpostT, const unsigned short* __restrict__ wscT,
    const float* __restrict__ features, const float* __restrict__ bpost,
    const float* __restrict__ bsc, const int* __restrict__ sample_idx,
    float* __restrict__ out, int mbase)
{
  extern __shared__ char smem[];
  const int t = threadIdx.x, w = t >> 6, l = t & 63, lr = l & 15, lg = l >> 4;
  const int mq = w >> 1, oh = w & 1;                // wave tile: rows mq*32.., cols oh*64..
  const int m0 = blockIdx.x * 128;                  // chunk-local row base

  f32x4 acc[2][4];
#pragma unroll
  for (int mi = 0; mi < 2; mi++)
#pragma unroll
  for (int ot = 0; ot < 4; ot++) acc[mi][ot] = (f32x4){0,0,0,0};

  const char* arows = (const char*)wfeat + (size_t)m0 * ROWB;
  const char* brows = (const char*)kpwT;

  // stage kt = 0 into buffer 0 (each thread: 2 A-chunks + 2 B-chunks of 16B)
#pragma unroll
  for (int h = 0; h < 2; h++) {
    int c = t + h*512; int row = c >> 3; int col = c & 7;
    int sinner = (col*16) ^ ((row & 7) << 4);
    g2l16(arows + (size_t)row * ROWB + sinner, smem + c*16);
    g2l16(brows + (size_t)row * ROWB + sinner, smem + 16384 + c*16);
  }
  __syncthreads();

  for (int kt = 0; kt < 30; kt++) {
    const int cur = kt & 1;
    const int nxt_off = (cur ^ 1) << 15;            // 0 or 32768
    if (kt < 29) {
      const int kb = (kt + 1) * 128;
#pragma unroll
      for (int h = 0; h < 2; h++) {
        int c = t + h*512; int row = c >> 3; int col = c & 7;
        int sinner = (col*16) ^ ((row & 7) << 4);
        g2l16(arows + (size_t)row * ROWB + kb + sinner, smem + nxt_off + c*16);
        g2l16(brows + (size_t)row * ROWB + kb + sinner, smem + nxt_off + 16384 + c*16);
      }
    }
    const char* Ab = smem + (cur << 15);
    const char* Bb = Ab + 16384;
#pragma unroll
    for (int ks = 0; ks < 2; ks++) {
      bf16x8 af[2];
#pragma unroll
      for (int mi = 0; mi < 2; mi++) {
        int m = mq*32 + mi*16 + lr;
        af[mi] = *(const bf16x8*)(Ab + m*128 + ((ks*64 + lg*16) ^ ((m & 7) << 4)));
      }
#pragma unroll
      for (int ot = 0; ot < 4; ot++) {
        int o = oh*64 + ot*16 + lr;
        bf16x8 bfr = *(const bf16x8*)(Bb + o*128 + ((ks*64 + lg*16) ^ ((o & 7) << 4)));
        acc[0][ot] = __builtin_amdgcn_mfma_f32_16x16x32_bf16(af[0], bfr, acc[0][ot], 0,0,0);
        acc[1][ot] = __builtin_amdgcn_mfma_f32_16x16x32_bf16(af[1], bfr, acc[1][ot], 0,0,0);
      }
    }
    __syncthreads();
  }

  // ---- epilogue staging: a2 = leaky(conv) bf16 [128][256B swz]; a3 = raw feats
  char* a2 = smem;                                   // 32 KB
  char* a3 = smem + 32768;                           // 16 KB
#pragma unroll
  for (int mi = 0; mi < 2; mi++)
#pragma unroll
  for (int ot = 0; ot < 4; ot++)
#pragma unroll
  for (int r = 0; r < 4; r++) {
    int m = mq*32 + mi*16 + lg*4 + r;
    int o = oh*64 + ot*16 + lr;
    *(unsigned short*)(a2 + m*256 + ((o*2) ^ ((m & 15) << 4))) =
        (unsigned short)f2bf(leaky(acc[mi][ot][r]));
  }
  for (int e = t; e < 1024; e += 512) {
    int r = e >> 3, seg = e & 7;
    int sidx = sample_idx[mbase + m0 + r];
    const float* src = features + (size_t)sidx * INF + seg*8;
    float4 f0 = *(const float4*)src, f1 = *(const float4*)(src + 4);
    uint4 pv = make_uint4(f2bf(f0.x) | (f2bf(f0.y) << 16),
                          f2bf(f0.z) | (f2bf(f0.w) << 16),
                          f2bf(f1.x) | (f2bf(f1.y) << 16),
                          f2bf(f1.z) | (f2bf(f1.w) << 16));
    *(uint4*)(a3 + r*128 + ((seg*16) ^ ((r & 7) << 4))) = pv;
  }
  __syncthreads();

  // ---- post (K=128) + shortcut (K=64), biases folded into C init ----
  f32x4 d[2][4];
#pragma unroll
  for (int ot = 0; ot < 4; ot++) {
    float bv = bpost[oh*64 + ot*16 + lr] + bsc[oh*64 + ot*16 + lr];
    f32x4 s = {bv, bv, bv, bv};
    d[0][ot] = s; d[1][ot] = s;
  }
#pragma unroll
  for (int ks = 0; ks < 4; ks++) {
    bf16x8 af[2];
#pragma unroll
    for (int mi = 0; mi < 2; mi++) {
      int m = mq*32 + mi*16 + lr;
      af[mi] = *(const bf16x8*)(a2 + m*256 + ((ks*64 + lg*16) ^ ((m & 15) << 4)));
    }
#pragma unroll
    for (int ot = 0; ot < 4; ot++) {
      bf16x8 b = *(const bf16x8*)(wpostT + (size_t)(oh*64 + ot*16 + lr) * OUTF + ks*32 + lg*8);
      d[0][ot] = __builtin_amdgcn_mfma_f32_16x16x32_bf16(af[0], b, d[0][ot], 0,0,0);
      d[1][ot] = __builtin_amdgcn_mfma_f32_16x16x32_bf16(af[1], b, d[1][ot], 0,0,0);
    }
  }
#pragma unroll
  for (int ks = 0; ks < 2; ks++) {
    bf16x8 af[2];
#pragma unroll
    for (int mi = 0; mi < 2; mi++) {
      int m = mq*32 + mi*16 + lr;
      af[mi] = *(const bf16x8*)(a3 + m*128 + ((ks*64 + lg*16) ^ ((m & 7) << 4)));
    }
#pragma unroll
    for (int ot = 0; ot < 4; ot++) {
      bf16x8 b = *(const bf16x8*)(wscT + (size_t)(oh*64 + ot*16 + lr) * INF + ks*32 + lg*8);
      d[0][ot] = __builtin_amdgcn_mfma_f32_16x16x32_bf16(af[0], b, d[0][ot], 0,0,0);
      d[1][ot] = __builtin_amdgcn_mfma_f32_16x16x32_bf16(af[1], b, d[1][ot], 0,0,0);
    }
  }
#pragma unroll
  for (int mi = 0; mi < 2; mi++)
#pragma unroll
  for (int ot = 0; ot < 4; ot++)
#pragma unroll
  for (int r = 0; r < 4; r++) {
    int m = mq*32 + mi*16 + lg*4 + r;
    int o = oh*64 + ot*16 + lr;
    out[(size_t)(mbase + m0 + m) * OUTF + o] = leaky(d[mi][ot][r]);
  }
}

extern "C" void kernel_launch(void* const* d_in, const int* in_sizes, int n_in,
                              void* d_out, int out_size, void* d_ws, size_t ws_size,
                              hipStream_t stream)
{
  const float* points   = (const float*)d_in[0];
  const float* features = (const float*)d_in[1];
  const float* W_pre    = (const float*)d_in[2];
  const float* b_pre    = (const float*)d_in[3];
  const float* kpts     = (const float*)d_in[4];
  const float* kpw      = (const float*)d_in[5];
  const float* W_post   = (const float*)d_in[6];
  const float* b_post   = (const float*)d_in[7];
  const float* W_sc     = (const float*)d_in[8];
  const float* b_sc     = (const float*)d_in[9];
  const int* sample_idx = (const int*)d_in[10];
  const int* nbr        = (const int*)d_in[11];
  float* out = (float*)d_out;

  char* ws = (char*)d_ws;
  unsigned short* featbf = (unsigned short*)ws;                 // 33,554,432 B
  unsigned short* kpwT   = (unsigned short*)(ws + 33554432);    //    491,520 B
  unsigned short* wpostT = (unsigned short*)(ws + 34045952);    //     32,768 B
  unsigned short* wscT   = (unsigned short*)(ws + 34078720);    //     16,384 B
  unsigned short* wpreT  = (unsigned short*)(ws + 34095104);    //     16,384 B
  unsigned short* wfeat  = (unsigned short*)(ws + 34111488);    // up to 240 MB

  double ext = (1.5 / 40.0) / (pow(15.0, 1.0 / 3.0) - 1.0) * 1.5;
  float inv_ext = (float)(1.0 / ext);

  // chunk wfeat if workspace is small (deterministic in ws_size)
  size_t fixed = 34111488ull;
  int chunks = 1;
  while (chunks < 32 && fixed + 251658240ull / (size_t)chunks > ws_size) chunks <<= 1;
  int msz = MTOT / chunks;

  (void)hipFuncSetAttribute((const void*)k_conv_67723,
                            hipFuncAttributeMaxDynamicSharedMemorySize, 65536);

  k_cvt_67723<<<1088, 256, 0, stream>>>(kpw, W_post, W_sc, W_pre, kpwT, wpostT, wscT, wpreT);
  k_pre_67723<<<1024, 256, 0, stream>>>(features, wpreT, b_pre, featbf);
  for (int ci = 0; ci < chunks; ci++) {
    int nwg = msz / 16;
    k_wfmma_67723<<<nwg, 256, 0, stream>>>(points, kpts, sample_idx, nbr, featbf,
                                           wfeat, inv_ext, ci*msz, nwg);
    k_conv_67723<<<msz/128, 512, 65536, stream>>>(wfeat, kpwT, wpostT, wscT, features,
                                                  b_post, b_sc, sample_idx, out, ci*msz);
  }
}